// Round 9
// baseline (201.928 us; speedup 1.0000x reference)
//
#include <hip/hip_runtime.h>

#define IN_F 512
#define OUT_F 1024
#define K_ACTIVE 11  // ceil(0.01 * 1024) serial MP steps
#define K_IN 6       // ceil(0.01 * 512) kwta winners

// ---- w [1024][512] f32 -> wT [513][1024] f32 (row 512 = zeros, odd-cnt pad) ----
// wT is 2.1 MB: fits per-XCD L2 (4 MiB) together with w (2 MB). R6 measured fp64
// wT (4.2 MB) thrashing L2 -> 156 MB HBM fetch, +34 us. Keep f32.
__global__ __launch_bounds__(256) void transpose_w_kernel(const float* __restrict__ w,
                                                          float* __restrict__ wT) {
    __shared__ float tile[32][33];
    const int tx = threadIdx.x & 31;
    const int ty = threadIdx.x >> 5;  // 0..7
    const int i0 = blockIdx.x * 32;
    const int j0 = blockIdx.y * 32;
#pragma unroll
    for (int k = 0; k < 4; ++k)
        tile[ty + 8 * k][tx] = w[(size_t)(j0 + ty + 8 * k) * IN_F + (i0 + tx)];
    __syncthreads();
#pragma unroll
    for (int k = 0; k < 4; ++k)
        wT[(size_t)(i0 + ty + 8 * k) * OUT_F + (j0 + tx)] = tile[tx][ty + 8 * k];
}
__global__ void zero_row_f_kernel(float* __restrict__ wT) {
    wT[(size_t)IN_F * OUT_F + blockIdx.x * 256 + threadIdx.x] = 0.0f;
}

#define NINF (-__builtin_huge_val())

// ---- wave-wide fp64 max via DPP; invalid lanes contribute their own value
//      (old = own halves, bound_ctrl = false -> identity for max) ----
template <int C>
__device__ __forceinline__ double dppmaxd(double v) {
    const long long b = __double_as_longlong(v);
    const int lo = (int)b, hi = (int)(b >> 32);
    const int slo = __builtin_amdgcn_update_dpp(lo, lo, C, 0xF, 0xF, false);
    const int shi = __builtin_amdgcn_update_dpp(hi, hi, C, 0xF, 0xF, false);
    const double o =
        __longlong_as_double(((long long)shi << 32) | (unsigned long long)(unsigned)slo);
    return fmax(v, o);
}
__device__ __forceinline__ double wave_dmax(double v) {
    v = dppmaxd<0x111>(v);  // row_shr:1
    v = dppmaxd<0x112>(v);  // row_shr:2
    v = dppmaxd<0x114>(v);  // row_shr:4
    v = dppmaxd<0x118>(v);  // row_shr:8
    v = dppmaxd<0x142>(v);  // row_bcast:15
    v = dppmaxd<0x143>(v);  // row_bcast:31 -> lane 63 holds wave max
    const long long b = __double_as_longlong(v);
    const int lo = __builtin_amdgcn_readlane((int)b, 63);
    const int hi = __builtin_amdgcn_readlane((int)(b >> 32), 63);
    return __longlong_as_double(((long long)hi << 32) | (unsigned long long)(unsigned)lo);
}

// half-row paired add (projection): rh[s] over j = wv*512 + (s>>2)*256 + lane*4 + (s&3)
__device__ __forceinline__ void half_add2(double* rh, const float* __restrict__ wT,
                                          int i0, int i1, int lane, int wv) {
    const float* p0 = wT + ((size_t)i0 << 10) + (wv << 9) + (lane << 2);
    const float* p1 = wT + ((size_t)i1 << 10) + (wv << 9) + (lane << 2);
    const float4 f0 = *(const float4*)(p0);
    const float4 f1 = *(const float4*)(p0 + 256);
    const float4 g0 = *(const float4*)(p1);
    const float4 g1 = *(const float4*)(p1 + 256);
    rh[0] += (double)f0.x + (double)g0.x;  rh[1] += (double)f0.y + (double)g0.y;
    rh[2] += (double)f0.z + (double)g0.z;  rh[3] += (double)f0.w + (double)g0.w;
    rh[4] += (double)f1.x + (double)g1.x;  rh[5] += (double)f1.y + (double)g1.y;
    rh[6] += (double)f1.z + (double)g1.z;  rh[7] += (double)f1.w + (double)g1.w;
}

// half-row axpy (residual update): same slot layout, 2 coalesced float4 loads
__device__ __forceinline__ void half_axpy(double* rh, const float* __restrict__ wT,
                                          int i, double sgn, int lane, int wv) {
    const float* rp = wT + ((size_t)i << 10) + (wv << 9) + (lane << 2);
    const float4 f0 = *(const float4*)(rp);
    const float4 f1 = *(const float4*)(rp + 256);
    rh[0] += sgn * (double)f0.x;  rh[1] += sgn * (double)f0.y;
    rh[2] += sgn * (double)f0.z;  rh[3] += sgn * (double)f0.w;
    rh[4] += sgn * (double)f1.x;  rh[5] += sgn * (double)f1.y;
    rh[6] += sgn * (double)f1.z;  rh[7] += sgn * (double)f1.w;
}

// MODE0 fallbacks (no workspace): strided gathers from row-major w
__device__ __forceinline__ void half_add0(double* rh, const float* __restrict__ w,
                                          int i, int lane, int wv) {
#pragma unroll
    for (int s = 0; s < 8; ++s) {
        const int j = (wv << 9) | ((s >> 2) << 8) | (lane << 2) | (s & 3);
        rh[s] += (double)w[(size_t)j * IN_F + i];
    }
}
__device__ __forceinline__ void half_axpy0(double* rh, const float* __restrict__ w,
                                           int i, double sgn, int lane, int wv) {
#pragma unroll
    for (int s = 0; s < 8; ++s) {
        const int j = (wv << 9) | ((s >> 2) << 8) | (lane << 2) | (s & 3);
        rh[s] += sgn * (double)w[(size_t)j * IN_F + i];
    }
}

// 2 waves per row. Wave wv owns residual half r[8]; wave 0 additionally owns the
// full v (vd[8]) and runs kwta wave-locally. Reductions are DIRECT fp64 max
// (v_max_f64) + ballot/readlane index resolve — no packed u64 keys (R8's key
// machinery was ~2x the issued ops). Exact fp64 cross-lane ties have prob ~0;
// within-lane lowest-index tie-break preserved by ascending slot scan.
template <int MODE>
__global__ __launch_bounds__(128) void bmp_kernel(const float* __restrict__ x,
                                                  const float* __restrict__ w,
                                                  const float* __restrict__ wT,
                                                  float* __restrict__ out, int rows) {
    __shared__ unsigned short act[IN_F + 8];
    __shared__ double gmax[2][2];  // parity-buffered argmax merge (value)
    __shared__ int gidx[2][2];     // parity-buffered argmax merge (index)
    __shared__ int msg[8];         // [1..6] = kwta winners from wave0
    const int lane = threadIdx.x & 63;
    const int wv = threadIdx.x >> 6;
    const int row = blockIdx.x;
    if (row >= rows) return;

    // ---- compacted active list of x row (both waves same ballots; wv0 writes) ----
    const float* xrow = x + (size_t)row * IN_F;
    int cnt = 0;
#pragma unroll
    for (int c = 0; c < IN_F / 64; ++c) {
        bool pbit = xrow[c * 64 + lane] != 0.0f;
        unsigned long long m = __ballot(pbit);
        int pre = __popcll(m & ((1ull << lane) - 1ull));
        if (wv == 0 && pbit) act[cnt + pre] = (unsigned short)(c * 64 + lane);
        cnt += __popcll(m);
    }
    if (wv == 0 && lane < 2) act[cnt + lane] = (unsigned short)IN_F;  // zero-row pad
    __syncthreads();

    // ---- r = 2 * x @ wT on own OUT-half (fp64; maintained incrementally) ----
    double r[8];
#pragma unroll
    for (int s = 0; s < 8; ++s) r[s] = 0.0;
    if constexpr (MODE == 1) {
#pragma unroll 1
        for (int k = 0; k < cnt; k += 2) half_add2(r, wT, act[k], act[k + 1], lane, wv);
    } else {
#pragma unroll 1
        for (int k = 0; k < cnt; ++k) half_add0(r, w, act[k], lane, wv);
    }
#pragma unroll
    for (int s = 0; s < 8; ++s) r[s] *= 2.0;

    double vd[8];  // full v = encoded @ W, live only on wave 0 (static indices)
#pragma unroll
    for (int p = 0; p < 8; ++p) vd[p] = 0.0;

    unsigned enc = 0;      // per-lane 8-bit slot mask over own OUT slots
    unsigned selmask = 0;  // wave0: final-step kdone (xr slots)
    int O0 = -1, O1 = -1, O2 = -1, O3 = -1, O4 = -1, O5 = -1;  // uniform

#pragma unroll 1
    for (int t = 0; t < K_ACTIVE; ++t) {
        // ---- argmax of residual over non-encoded j (lambd => exclusion) ----
        {
            double lv = NINF;
#pragma unroll
            for (int s = 0; s < 8; ++s)
                lv = fmax(lv, (enc & (1u << s)) ? NINF : r[s]);
            const double gw = wave_dmax(lv);  // uniform in wave
            int bi = 0;                       // lowest-j slot matching gw (j asc in s)
#pragma unroll
            for (int s = 7; s >= 0; --s)
                if (!(enc & (1u << s)) && r[s] == gw) bi = s;
            const unsigned long long tb = __ballot(lv == gw);
            const int L = (int)__ffsll((long long)tb) - 1;
            const int biL = __builtin_amdgcn_readlane(bi, L);
            const int jw = (wv << 9) | ((biL >> 2) << 8) | (L << 2) | (biL & 3);
            if (lane == 0) {
                gmax[t & 1][wv] = gw;
                gidx[t & 1][wv] = jw;
            }
        }
        __syncthreads();  // B1: merge the two half-maxima
        const double g0 = gmax[t & 1][0], g1 = gmax[t & 1][1];
        const int bestj = __builtin_amdgcn_readfirstlane(
            (g1 > g0) ? gidx[t & 1][1] : gidx[t & 1][0]);
        if ((bestj >> 9) == wv && ((bestj >> 2) & 63) == lane)
            enc |= 1u << ((((bestj >> 8) & 1) << 2) | (bestj & 3));

        if (wv == 0) {
            // ---- v += W[bestj][:] (two 1KB-contiguous float4 loads) ----
            const float* wr = w + ((size_t)bestj << 9) + (lane << 2);
            const float4 f0 = *(const float4*)wr;
            const float4 f1 = *(const float4*)(wr + 256);
            vd[0] += (double)f0.x;  vd[1] += (double)f0.y;
            vd[2] += (double)f0.z;  vd[3] += (double)f0.w;
            vd[4] += (double)f1.x;  vd[5] += (double)f1.y;
            vd[6] += (double)f1.z;  vd[7] += (double)f1.w;

            // ---- kwta: top-6 of v, 6 wave-local fp64-max rounds ----
            unsigned kdone = 0;
#pragma unroll
            for (int s2 = 0; s2 < K_IN; ++s2) {
                double lk = NINF;
#pragma unroll
                for (int p = 0; p < 8; ++p)
                    lk = fmax(lk, (kdone & (1u << p)) ? NINF : vd[p]);
                const double gk = wave_dmax(lk);
                int bp = 0;  // lowest-i slot matching gk (i asc in p)
#pragma unroll
                for (int p = 7; p >= 0; --p)
                    if (!(kdone & (1u << p)) && vd[p] == gk) bp = p;
                const unsigned long long tb = __ballot(lk == gk);
                const int L2 = (int)__ffsll((long long)tb) - 1;
                const int bpL = __builtin_amdgcn_readlane(bp, L2);
                const int n = ((bpL >> 2) << 8) | (L2 << 2) | (bpL & 3);
                if (lane == 0) msg[1 + s2] = n;
                if (lane == L2) kdone |= 1u << bpL;
            }
            if (t == K_ACTIVE - 1) selmask = kdone;
        }
        __syncthreads();  // B2: N winners -> both waves
        if (t < K_ACTIVE - 1) {
            const int N0 = __builtin_amdgcn_readfirstlane(msg[1]);
            const int N1 = __builtin_amdgcn_readfirstlane(msg[2]);
            const int N2 = __builtin_amdgcn_readfirstlane(msg[3]);
            const int N3 = __builtin_amdgcn_readfirstlane(msg[4]);
            const int N4 = __builtin_amdgcn_readfirstlane(msg[5]);
            const int N5 = __builtin_amdgcn_readfirstlane(msg[6]);
            // ---- incremental residual update on own half: set-diff of xr ----
            if (t == 0) {
                if constexpr (MODE == 1) {
                    half_axpy(r, wT, N0, -1.0, lane, wv);
                    half_axpy(r, wT, N1, -1.0, lane, wv);
                    half_axpy(r, wT, N2, -1.0, lane, wv);
                    half_axpy(r, wT, N3, -1.0, lane, wv);
                    half_axpy(r, wT, N4, -1.0, lane, wv);
                    half_axpy(r, wT, N5, -1.0, lane, wv);
                } else {
                    half_axpy0(r, w, N0, -1.0, lane, wv);
                    half_axpy0(r, w, N1, -1.0, lane, wv);
                    half_axpy0(r, w, N2, -1.0, lane, wv);
                    half_axpy0(r, w, N3, -1.0, lane, wv);
                    half_axpy0(r, w, N4, -1.0, lane, wv);
                    half_axpy0(r, w, N5, -1.0, lane, wv);
                }
            } else {
#pragma unroll
                for (int a2 = 0; a2 < 6; ++a2) {
                    const int o = (a2 == 0) ? O0 : (a2 == 1) ? O1 : (a2 == 2) ? O2
                                  : (a2 == 3) ? O3 : (a2 == 4) ? O4 : O5;
                    const bool stay = (o == N0) | (o == N1) | (o == N2) |
                                      (o == N3) | (o == N4) | (o == N5);
                    if (!stay) {
                        if constexpr (MODE == 1) half_axpy(r, wT, o, 1.0, lane, wv);
                        else half_axpy0(r, w, o, 1.0, lane, wv);
                    }
                }
#pragma unroll
                for (int b2 = 0; b2 < 6; ++b2) {
                    const int n = (b2 == 0) ? N0 : (b2 == 1) ? N1 : (b2 == 2) ? N2
                                  : (b2 == 3) ? N3 : (b2 == 4) ? N4 : N5;
                    const bool was = (n == O0) | (n == O1) | (n == O2) |
                                     (n == O3) | (n == O4) | (n == O5);
                    if (!was) {
                        if constexpr (MODE == 1) half_axpy(r, wT, n, -1.0, lane, wv);
                        else half_axpy0(r, w, n, -1.0, lane, wv);
                    }
                }
            }
            O0 = N0; O1 = N1; O2 = N2; O3 = N3; O4 = N4; O5 = N5;
        }
    }

    // ---- outputs: encoded halves (each wave), xr (wave0), coalesced float4 ----
    float* oe = out + (size_t)row * OUT_F + (wv << 9) + (lane << 2);
#pragma unroll
    for (int c = 0; c < 2; ++c) {
        float4 v;
        v.x = (enc & (1u << (4 * c + 0))) ? 1.0f : 0.0f;
        v.y = (enc & (1u << (4 * c + 1))) ? 1.0f : 0.0f;
        v.z = (enc & (1u << (4 * c + 2))) ? 1.0f : 0.0f;
        v.w = (enc & (1u << (4 * c + 3))) ? 1.0f : 0.0f;
        *(float4*)(oe + (c << 8)) = v;
    }
    if (wv == 0) {
        float* ox = out + (size_t)rows * OUT_F + (size_t)row * IN_F + (lane << 2);
#pragma unroll
        for (int c = 0; c < 2; ++c) {
            float4 v;
            v.x = (selmask & (1u << (4 * c + 0))) ? 1.0f : 0.0f;
            v.y = (selmask & (1u << (4 * c + 1))) ? 1.0f : 0.0f;
            v.z = (selmask & (1u << (4 * c + 2))) ? 1.0f : 0.0f;
            v.w = (selmask & (1u << (4 * c + 3))) ? 1.0f : 0.0f;
            *(float4*)(ox + (c << 8)) = v;
        }
    }
}

extern "C" void kernel_launch(void* const* d_in, const int* in_sizes, int n_in,
                              void* d_out, int out_size, void* d_ws, size_t ws_size,
                              hipStream_t stream) {
    const float* x = (const float*)d_in[0];
    const float* w = (const float*)d_in[1];
    float* out = (float*)d_out;
    const int rows = in_sizes[0] / IN_F;  // 4096

    const size_t need_f = (size_t)(IN_F + 1) * OUT_F * sizeof(float);  // 2.1 MB

    if (d_ws != nullptr && ws_size >= need_f) {
        float* wT = (float*)d_ws;
        transpose_w_kernel<<<dim3(IN_F / 32, OUT_F / 32), 256, 0, stream>>>(w, wT);
        zero_row_f_kernel<<<OUT_F / 256, 256, 0, stream>>>(wT);
        bmp_kernel<1><<<rows, 128, 0, stream>>>(x, w, wT, out, rows);
    } else {
        bmp_kernel<0><<<rows, 128, 0, stream>>>(x, w, nullptr, out, rows);
    }
}

// Round 10
// 153.697 us; speedup vs baseline: 1.3138x; 1.3138x over previous
//
#include <hip/hip_runtime.h>

#define IN_F 512
#define OUT_F 1024
#define K_ACTIVE 11  // ceil(0.01 * 1024) serial MP steps
#define K_IN 6       // ceil(0.01 * 512) kwta winners

// ---- w [1024][512] f32 -> wT [513][1024] f32 (row 512 = zeros, odd-cnt pad) ----
// wT is 2.1 MB: fits per-XCD L2 (4 MiB) together with w (2 MB). R6 measured fp64
// wT (4.2 MB) thrashing L2 -> 156 MB HBM fetch, +34 us. Keep f32.
__global__ __launch_bounds__(256) void transpose_w_kernel(const float* __restrict__ w,
                                                          float* __restrict__ wT) {
    __shared__ float tile[32][33];
    const int tx = threadIdx.x & 31;
    const int ty = threadIdx.x >> 5;  // 0..7
    const int i0 = blockIdx.x * 32;
    const int j0 = blockIdx.y * 32;
#pragma unroll
    for (int k = 0; k < 4; ++k)
        tile[ty + 8 * k][tx] = w[(size_t)(j0 + ty + 8 * k) * IN_F + (i0 + tx)];
    __syncthreads();
#pragma unroll
    for (int k = 0; k < 4; ++k)
        wT[(size_t)(i0 + ty + 8 * k) * OUT_F + (j0 + tx)] = tile[tx][ty + 8 * k];
}
__global__ void zero_row_f_kernel(float* __restrict__ wT) {
    wT[(size_t)IN_F * OUT_F + blockIdx.x * 256 + threadIdx.x] = 0.0f;
}

// ---- order-preserving fp64 -> u64 key, low bits carry reversed index ----
// max(key) == max value; ties -> lowest index (exact reference tie-break).
__device__ __forceinline__ unsigned long long pack_key(double v, unsigned rev,
                                                       unsigned long long mask) {
    unsigned long long b = (unsigned long long)__double_as_longlong(v);
    unsigned long long m =
        (unsigned long long)((long long)b >> 63) | 0x8000000000000000ull;
    unsigned long long u = b ^ m;  // monotonic total order
    return (u & ~mask) | (unsigned long long)rev;
}

// ---- monotonic u32 key from the f64 HIGH word (coarse: 20 mantissa bits) ----
__device__ __forceinline__ unsigned hi_key(double v) {
    const int hi = __double2hiint(v);
    return (unsigned)hi ^ ((unsigned)(hi >> 31) | 0x80000000u);
}

// ---- wave max of u32 via DPP chain (bound_ctrl=true: invalid lanes -> 0) ----
template <int C>
__device__ __forceinline__ unsigned maxdpp(unsigned v) {
    unsigned t = (unsigned)__builtin_amdgcn_update_dpp(0, (int)v, C, 0xF, 0xF, true);
    return t > v ? t : v;
}
__device__ __forceinline__ unsigned wave_umax(unsigned v) {
    v = maxdpp<0x111>(v);  // row_shr:1
    v = maxdpp<0x112>(v);  // row_shr:2
    v = maxdpp<0x114>(v);  // row_shr:4
    v = maxdpp<0x118>(v);  // row_shr:8
    v = maxdpp<0x142>(v);  // row_bcast:15
    v = maxdpp<0x143>(v);  // row_bcast:31 -> lane 63 holds wave max
    return (unsigned)__builtin_amdgcn_readlane((int)v, 63);
}

// ---- exact wave max of u64 key (slow path): high32 chain + tie resolve ----
__device__ __forceinline__ unsigned long long wave_max_key(unsigned long long k) {
    const unsigned h = (unsigned)(k >> 32), l = (unsigned)k;
    const unsigned gh = wave_umax(h);
    const unsigned long long tied = __ballot(h == gh);
    unsigned gl;
    if (__popcll(tied) == 1) {
        gl = (unsigned)__builtin_amdgcn_readlane((int)l,
                                                 (int)__ffsll((long long)tied) - 1);
    } else {
        gl = wave_umax((h == gh) ? l : 0u);
    }
    return ((unsigned long long)gh << 32) | gl;
}

// half-row paired add (projection): rh[s] over j = wv*512 + (s>>2)*256 + lane*4 + (s&3)
__device__ __forceinline__ void half_add2(double* rh, const float* __restrict__ wT,
                                          int i0, int i1, int lane, int wv) {
    const float* p0 = wT + ((size_t)i0 << 10) + (wv << 9) + (lane << 2);
    const float* p1 = wT + ((size_t)i1 << 10) + (wv << 9) + (lane << 2);
    const float4 f0 = *(const float4*)(p0);
    const float4 f1 = *(const float4*)(p0 + 256);
    const float4 g0 = *(const float4*)(p1);
    const float4 g1 = *(const float4*)(p1 + 256);
    rh[0] += (double)f0.x + (double)g0.x;  rh[1] += (double)f0.y + (double)g0.y;
    rh[2] += (double)f0.z + (double)g0.z;  rh[3] += (double)f0.w + (double)g0.w;
    rh[4] += (double)f1.x + (double)g1.x;  rh[5] += (double)f1.y + (double)g1.y;
    rh[6] += (double)f1.z + (double)g1.z;  rh[7] += (double)f1.w + (double)g1.w;
}

// half-row axpy (residual update): same slot layout, 2 coalesced float4 loads
__device__ __forceinline__ void half_axpy(double* rh, const float* __restrict__ wT,
                                          int i, double sgn, int lane, int wv) {
    const float* rp = wT + ((size_t)i << 10) + (wv << 9) + (lane << 2);
    const float4 f0 = *(const float4*)(rp);
    const float4 f1 = *(const float4*)(rp + 256);
    rh[0] += sgn * (double)f0.x;  rh[1] += sgn * (double)f0.y;
    rh[2] += sgn * (double)f0.z;  rh[3] += sgn * (double)f0.w;
    rh[4] += sgn * (double)f1.x;  rh[5] += sgn * (double)f1.y;
    rh[6] += sgn * (double)f1.z;  rh[7] += sgn * (double)f1.w;
}

// MODE0 fallbacks (no workspace): strided gathers from row-major w
__device__ __forceinline__ void half_add0(double* rh, const float* __restrict__ w,
                                          int i, int lane, int wv) {
#pragma unroll
    for (int s = 0; s < 8; ++s) {
        const int j = (wv << 9) | ((s >> 2) << 8) | (lane << 2) | (s & 3);
        rh[s] += (double)w[(size_t)j * IN_F + i];
    }
}
__device__ __forceinline__ void half_axpy0(double* rh, const float* __restrict__ w,
                                           int i, double sgn, int lane, int wv) {
#pragma unroll
    for (int s = 0; s < 8; ++s) {
        const int j = (wv << 9) | ((s >> 2) << 8) | (lane << 2) | (s & 3);
        rh[s] += sgn * (double)w[(size_t)j * IN_F + i];
    }
}

// 2 waves per row (R8 structure). Reductions: u32 high-word keys fast path +
// exact u64 slow path on ties (P ~ 2^-20/round) -> exact reference semantics at
// ~0.5x the issued ops of the all-u64 version (R8) and none of R9's fp64-max
// and index-scan latency tails.
template <int MODE>
__global__ __launch_bounds__(128) void bmp_kernel(const float* __restrict__ x,
                                                  const float* __restrict__ w,
                                                  const float* __restrict__ wT,
                                                  float* __restrict__ out, int rows) {
    __shared__ unsigned short act[IN_F + 8];
    __shared__ unsigned gu32[2][2];        // parity: fast argmax merge (u32 key)
    __shared__ int gjw[2][2];              // parity: fast argmax merge (index)
    __shared__ unsigned long long kx[2];   // slow cross-wave u64 merge
    __shared__ int msg[8];                 // [1..6] = kwta winners from wave0
    const int lane = threadIdx.x & 63;
    const int wv = threadIdx.x >> 6;
    const int row = blockIdx.x;
    if (row >= rows) return;

    // ---- compacted active list of x row (both waves same ballots; wv0 writes) ----
    const float* xrow = x + (size_t)row * IN_F;
    int cnt = 0;
#pragma unroll
    for (int c = 0; c < IN_F / 64; ++c) {
        bool pbit = xrow[c * 64 + lane] != 0.0f;
        unsigned long long m = __ballot(pbit);
        int pre = __popcll(m & ((1ull << lane) - 1ull));
        if (wv == 0 && pbit) act[cnt + pre] = (unsigned short)(c * 64 + lane);
        cnt += __popcll(m);
    }
    if (wv == 0 && lane < 2) act[cnt + lane] = (unsigned short)IN_F;  // zero-row pad
    __syncthreads();

    // ---- r = 2 * x @ wT on own OUT-half (fp64; maintained incrementally) ----
    double r[8];
#pragma unroll
    for (int s = 0; s < 8; ++s) r[s] = 0.0;
    if constexpr (MODE == 1) {
#pragma unroll 1
        for (int k = 0; k < cnt; k += 2) half_add2(r, wT, act[k], act[k + 1], lane, wv);
    } else {
#pragma unroll 1
        for (int k = 0; k < cnt; ++k) half_add0(r, w, act[k], lane, wv);
    }
#pragma unroll
    for (int s = 0; s < 8; ++s) r[s] *= 2.0;

    double vd[8];  // full v = encoded @ W, live only on wave 0 (static indices)
#pragma unroll
    for (int p = 0; p < 8; ++p) vd[p] = 0.0;

    unsigned enc = 0;      // per-lane 8-bit slot mask over own OUT slots
    unsigned selmask = 0;  // wave0: final-step xr slots
    int O0 = -1, O1 = -1, O2 = -1, O3 = -1, O4 = -1, O5 = -1;  // uniform

#pragma unroll 1
    for (int t = 0; t < K_ACTIVE; ++t) {
        // ---- argmax of residual over non-encoded j (lambd => exclusion) ----
        unsigned k8[8];  // transient u32 keys, alive through the cross merge
#pragma unroll
        for (int s = 0; s < 8; ++s) {
            const unsigned key = hi_key(r[s]);
            k8[s] = (enc & (1u << s)) ? 0u : key;
        }
        {
            unsigned lm = k8[0];
#pragma unroll
            for (int s = 1; s < 8; ++s) lm = k8[s] > lm ? k8[s] : lm;
            const unsigned g = wave_umax(lm);
            const unsigned long long tied = __ballot(lm == g);
            unsigned mm = 0;
#pragma unroll
            for (int s = 0; s < 8; ++s) mm |= (k8[s] == g) ? (1u << s) : 0u;
            const int L = (int)__ffsll((long long)tied) - 1;
            const unsigned mmL = (unsigned)__builtin_amdgcn_readlane((int)mm, L);
            int jw;
            if (__builtin_expect((__popcll(tied) == 1) && !(mmL & (mmL - 1)), 1)) {
                const int bi = __ffs(mmL) - 1;  // slot asc == j asc within lane
                jw = (wv << 9) | ((bi >> 2) << 8) | (L << 2) | (bi & 3);
            } else {  // exact intra-wave resolve among u32-tied candidates
                unsigned long long kb = 0;
#pragma unroll
                for (int s = 0; s < 8; ++s) {
                    const int j = (wv << 9) | ((s >> 2) << 8) | (lane << 2) | (s & 3);
                    const unsigned long long fk =
                        pack_key(r[s], 1023u ^ (unsigned)j, 1023ull);
                    kb = (k8[s] == g && fk > kb) ? fk : kb;
                }
                const unsigned long long gk = wave_max_key(kb);
                jw = 1023 ^ (int)(gk & 1023ull);
            }
            if (lane == 0) {
                gu32[t & 1][wv] = g;
                gjw[t & 1][wv] = jw;
            }
        }
        __syncthreads();  // B1: merge the two half-maxima
        const unsigned ga = gu32[t & 1][0], gb = gu32[t & 1][1];
        int bestj;
        if (__builtin_expect(ga != gb, 1)) {  // u32 strict order is f64-faithful
            bestj = (gb > ga) ? gjw[t & 1][1] : gjw[t & 1][0];
        } else {  // rare: exact cross-wave u64 merge (uniform branch, own barrier)
            unsigned long long kb = 0;
#pragma unroll
            for (int s = 0; s < 8; ++s) {
                const int j = (wv << 9) | ((s >> 2) << 8) | (lane << 2) | (s & 3);
                const unsigned long long fk =
                    pack_key(r[s], 1023u ^ (unsigned)j, 1023ull);
                kb = (k8[s] == ga && fk > kb) ? fk : kb;
            }
            const unsigned long long wm = wave_max_key(kb);
            if (lane == 0) kx[wv] = wm;
            __syncthreads();
            const unsigned long long A = kx[0], B = kx[1];
            bestj = 1023 ^ (int)((A > B ? A : B) & 1023ull);
        }
        bestj = __builtin_amdgcn_readfirstlane(bestj);
        if ((bestj >> 9) == wv && ((bestj >> 2) & 63) == lane)
            enc |= 1u << ((((bestj >> 8) & 1) << 2) | (bestj & 3));

        if (wv == 0) {
            // ---- v += W[bestj][:] (two 1KB-contiguous float4 loads) ----
            const float* wr = w + ((size_t)bestj << 9) + (lane << 2);
            const float4 f0 = *(const float4*)wr;
            const float4 f1 = *(const float4*)(wr + 256);
            vd[0] += (double)f0.x;  vd[1] += (double)f0.y;
            vd[2] += (double)f0.z;  vd[3] += (double)f0.w;
            vd[4] += (double)f1.x;  vd[5] += (double)f1.y;
            vd[6] += (double)f1.z;  vd[7] += (double)f1.w;

            // ---- kwta: top-6 of v, u32 keys packed once, 6 wave-local rounds ----
            unsigned kk[8];  // transient
#pragma unroll
            for (int p = 0; p < 8; ++p) kk[p] = hi_key(vd[p]);
#pragma unroll
            for (int s2 = 0; s2 < K_IN; ++s2) {
                unsigned lm = kk[0];
#pragma unroll
                for (int p = 1; p < 8; ++p) lm = kk[p] > lm ? kk[p] : lm;
                const unsigned g = wave_umax(lm);
                const unsigned long long tied = __ballot(lm == g);
                unsigned mm = 0;
#pragma unroll
                for (int p = 0; p < 8; ++p) mm |= (kk[p] == g) ? (1u << p) : 0u;
                const int L2 = (int)__ffsll((long long)tied) - 1;
                const unsigned mmL = (unsigned)__builtin_amdgcn_readlane((int)mm, L2);
                int n;
                if (__builtin_expect((__popcll(tied) == 1) && !(mmL & (mmL - 1)), 1)) {
                    const int bp = __ffs(mmL) - 1;
                    n = ((bp >> 2) << 8) | (L2 << 2) | (bp & 3);
                    // unique candidate: clear by value (exactly one slot matches)
#pragma unroll
                    for (int p = 0; p < 8; ++p) kk[p] = (kk[p] == g) ? 0u : kk[p];
                } else {  // exact resolve among u32-tied candidates
                    unsigned long long kb = 0;
#pragma unroll
                    for (int p = 0; p < 8; ++p) {
                        const int i = ((p >> 2) << 8) | (lane << 2) | (p & 3);
                        const unsigned long long fk =
                            pack_key(vd[p], 511u ^ (unsigned)i, 511ull);
                        kb = (kk[p] == g && fk > kb) ? fk : kb;
                    }
                    const unsigned long long gk = wave_max_key(kb);
                    n = 511 ^ (int)(gk & 511ull);
                    const int ln = (n >> 2) & 63;
                    const int bp = (((n >> 8) & 1) << 2) | (n & 3);
#pragma unroll
                    for (int p = 0; p < 8; ++p)
                        kk[p] = (lane == ln && p == bp) ? 0u : kk[p];
                }
                if (lane == 0) msg[1 + s2] = n;
            }
            if (t == K_ACTIVE - 1) {
                selmask = 0;  // cleared keys are 0 (0 unreachable for real values)
#pragma unroll
                for (int p = 0; p < 8; ++p) selmask |= (kk[p] == 0u) ? (1u << p) : 0u;
            }
        }
        __syncthreads();  // B2: N winners -> both waves
        if (t < K_ACTIVE - 1) {
            const int N0 = __builtin_amdgcn_readfirstlane(msg[1]);
            const int N1 = __builtin_amdgcn_readfirstlane(msg[2]);
            const int N2 = __builtin_amdgcn_readfirstlane(msg[3]);
            const int N3 = __builtin_amdgcn_readfirstlane(msg[4]);
            const int N4 = __builtin_amdgcn_readfirstlane(msg[5]);
            const int N5 = __builtin_amdgcn_readfirstlane(msg[6]);
            // ---- incremental residual update on own half: set-diff of xr ----
            if (t == 0) {
                if constexpr (MODE == 1) {
                    half_axpy(r, wT, N0, -1.0, lane, wv);
                    half_axpy(r, wT, N1, -1.0, lane, wv);
                    half_axpy(r, wT, N2, -1.0, lane, wv);
                    half_axpy(r, wT, N3, -1.0, lane, wv);
                    half_axpy(r, wT, N4, -1.0, lane, wv);
                    half_axpy(r, wT, N5, -1.0, lane, wv);
                } else {
                    half_axpy0(r, w, N0, -1.0, lane, wv);
                    half_axpy0(r, w, N1, -1.0, lane, wv);
                    half_axpy0(r, w, N2, -1.0, lane, wv);
                    half_axpy0(r, w, N3, -1.0, lane, wv);
                    half_axpy0(r, w, N4, -1.0, lane, wv);
                    half_axpy0(r, w, N5, -1.0, lane, wv);
                }
            } else {
#pragma unroll
                for (int a2 = 0; a2 < 6; ++a2) {
                    const int o = (a2 == 0) ? O0 : (a2 == 1) ? O1 : (a2 == 2) ? O2
                                  : (a2 == 3) ? O3 : (a2 == 4) ? O4 : O5;
                    const bool stay = (o == N0) | (o == N1) | (o == N2) |
                                      (o == N3) | (o == N4) | (o == N5);
                    if (!stay) {
                        if constexpr (MODE == 1) half_axpy(r, wT, o, 1.0, lane, wv);
                        else half_axpy0(r, w, o, 1.0, lane, wv);
                    }
                }
#pragma unroll
                for (int b2 = 0; b2 < 6; ++b2) {
                    const int n = (b2 == 0) ? N0 : (b2 == 1) ? N1 : (b2 == 2) ? N2
                                  : (b2 == 3) ? N3 : (b2 == 4) ? N4 : N5;
                    const bool was = (n == O0) | (n == O1) | (n == O2) |
                                     (n == O3) | (n == O4) | (n == O5);
                    if (!was) {
                        if constexpr (MODE == 1) half_axpy(r, wT, n, -1.0, lane, wv);
                        else half_axpy0(r, w, n, -1.0, lane, wv);
                    }
                }
            }
            O0 = N0; O1 = N1; O2 = N2; O3 = N3; O4 = N4; O5 = N5;
        }
    }

    // ---- outputs: encoded halves (each wave), xr (wave0), coalesced float4 ----
    float* oe = out + (size_t)row * OUT_F + (wv << 9) + (lane << 2);
#pragma unroll
    for (int c = 0; c < 2; ++c) {
        float4 v;
        v.x = (enc & (1u << (4 * c + 0))) ? 1.0f : 0.0f;
        v.y = (enc & (1u << (4 * c + 1))) ? 1.0f : 0.0f;
        v.z = (enc & (1u << (4 * c + 2))) ? 1.0f : 0.0f;
        v.w = (enc & (1u << (4 * c + 3))) ? 1.0f : 0.0f;
        *(float4*)(oe + (c << 8)) = v;
    }
    if (wv == 0) {
        float* ox = out + (size_t)rows * OUT_F + (size_t)row * IN_F + (lane << 2);
#pragma unroll
        for (int c = 0; c < 2; ++c) {
            float4 v;
            v.x = (selmask & (1u << (4 * c + 0))) ? 1.0f : 0.0f;
            v.y = (selmask & (1u << (4 * c + 1))) ? 1.0f : 0.0f;
            v.z = (selmask & (1u << (4 * c + 2))) ? 1.0f : 0.0f;
            v.w = (selmask & (1u << (4 * c + 3))) ? 1.0f : 0.0f;
            *(float4*)(ox + (c << 8)) = v;
        }
    }
}

extern "C" void kernel_launch(void* const* d_in, const int* in_sizes, int n_in,
                              void* d_out, int out_size, void* d_ws, size_t ws_size,
                              hipStream_t stream) {
    const float* x = (const float*)d_in[0];
    const float* w = (const float*)d_in[1];
    float* out = (float*)d_out;
    const int rows = in_sizes[0] / IN_F;  // 4096

    const size_t need_f = (size_t)(IN_F + 1) * OUT_F * sizeof(float);  // 2.1 MB

    if (d_ws != nullptr && ws_size >= need_f) {
        float* wT = (float*)d_ws;
        transpose_w_kernel<<<dim3(IN_F / 32, OUT_F / 32), 256, 0, stream>>>(w, wT);
        zero_row_f_kernel<<<OUT_F / 256, 256, 0, stream>>>(wT);
        bmp_kernel<1><<<rows, 128, 0, stream>>>(x, w, wT, out, rows);
    } else {
        bmp_kernel<0><<<rows, 128, 0, stream>>>(x, w, nullptr, out, rows);
    }
}